// Round 2
// baseline (6501.014 us; speedup 1.0000x reference)
//
#include <hip/hip_runtime.h>

#define D 128

// ============================================================================
// Fused dual-source GEMM:  out[M][128] = act( X1 @ W1^T + X2 @ W2^T + bias )
//   W row j lives at W[j*ws + k], k = 0..127 (ws = row stride: 128 or 256 for
//   concat-weights where the second half is W+128).
//   ACT: 0 = none, 1 = relu, 2 = leaky(0.2)
//   Safe for out == X1 / out == X2 (tiles fully staged before epilogue write;
//   blocks only write their own 64 rows).
// ============================================================================
template<int ACT, bool DUAL>
__global__ __launch_bounds__(256, 2)
void gemm_dual(const float* __restrict__ X1, const float* __restrict__ W1, int ws1,
               const float* __restrict__ X2, const float* __restrict__ W2, int ws2,
               const float* __restrict__ bias, float* __restrict__ out, int M)
{
    __shared__ float sXT[D][68];    // X^T tile: [k][r], 64 rows, pad 68
    __shared__ float sWT[64][132];  // W^T half: [k - kh*64][c], pad 132
    const int tid  = threadIdx.x;
    const int row0 = blockIdx.x * 64;
    const int c0 = (tid & 31) * 4;   // 4 output cols
    const int r0 = (tid >> 5) * 8;   // 8 output rows
    float acc[8][4] = {};

    #pragma unroll
    for (int s = 0; s < (DUAL ? 2 : 1); ++s) {
        const float* __restrict__ X = s ? X2 : X1;
        const float* __restrict__ W = s ? W2 : W1;
        const int ws = s ? ws2 : ws1;
        __syncthreads();   // protect sXT against readers from previous source
        // ---- stage X^T (64 rows x 128 k) ----
        #pragma unroll
        for (int i = 0; i < 8; ++i) {
            int idx = tid + i * 256;      // 2048 float4 in tile
            int r  = idx >> 5;            // 0..63
            int kq = idx & 31;            // float4 index along k
            float4 v = make_float4(0.f, 0.f, 0.f, 0.f);
            int gr = row0 + r;
            if (gr < M) v = *reinterpret_cast<const float4*>(X + (size_t)gr * D + kq * 4);
            sXT[kq*4+0][r] = v.x;
            sXT[kq*4+1][r] = v.y;
            sXT[kq*4+2][r] = v.z;
            sXT[kq*4+3][r] = v.w;
        }
        for (int kh = 0; kh < 2; ++kh) {
            __syncthreads();   // sXT staged / previous sWT consumers done
            {   // ---- stage W^T half: sWT[kk][c] = W[c*ws + kh*64 + kk] ----
                int c   = tid >> 1;
                int kkb = (tid & 1) * 32;
                const float* wr = W + (size_t)c * ws + kh * 64 + kkb;
                #pragma unroll
                for (int j = 0; j < 8; ++j) {
                    float4 v = *reinterpret_cast<const float4*>(wr + j * 4);
                    sWT[kkb + j*4 + 0][c] = v.x;
                    sWT[kkb + j*4 + 1][c] = v.y;
                    sWT[kkb + j*4 + 2][c] = v.z;
                    sWT[kkb + j*4 + 3][c] = v.w;
                }
            }
            __syncthreads();
            #pragma unroll 8
            for (int kk = 0; kk < 64; ++kk) {
                const int k = kh * 64 + kk;
                const float4 a0 = *reinterpret_cast<const float4*>(&sXT[k][r0]);
                const float4 a1 = *reinterpret_cast<const float4*>(&sXT[k][r0 + 4]);
                const float4 w  = *reinterpret_cast<const float4*>(&sWT[kk][c0]);
                const float av[8] = {a0.x, a0.y, a0.z, a0.w, a1.x, a1.y, a1.z, a1.w};
                #pragma unroll
                for (int j = 0; j < 8; ++j) {
                    acc[j][0] = fmaf(av[j], w.x, acc[j][0]);
                    acc[j][1] = fmaf(av[j], w.y, acc[j][1]);
                    acc[j][2] = fmaf(av[j], w.z, acc[j][2]);
                    acc[j][3] = fmaf(av[j], w.w, acc[j][3]);
                }
            }
        }
    }
    const float4 bv = *reinterpret_cast<const float4*>(bias + c0);
    #pragma unroll
    for (int j = 0; j < 8; ++j) {
        int gr = row0 + r0 + j;
        if (gr < M) {
            float4 o;
            o.x = acc[j][0] + bv.x;
            o.y = acc[j][1] + bv.y;
            o.z = acc[j][2] + bv.z;
            o.w = acc[j][3] + bv.w;
            if (ACT == 1) {
                o.x = fmaxf(o.x, 0.f); o.y = fmaxf(o.y, 0.f);
                o.z = fmaxf(o.z, 0.f); o.w = fmaxf(o.w, 0.f);
            } else if (ACT == 2) {
                o.x = o.x >= 0.f ? o.x : 0.2f * o.x;
                o.y = o.y >= 0.f ? o.y : 0.2f * o.y;
                o.z = o.z >= 0.f ? o.z : 0.2f * o.z;
                o.w = o.w >= 0.f ? o.w : 0.2f * o.w;
            }
            *reinterpret_cast<float4*>(out + (size_t)gr * D + c0) = o;
        }
    }
}

// ============================================================================
// Edge scatter: agg[dst] += X[src] * (ew ? ew[e] : 1);  deg[dst] += 1
// 32 lanes per edge, float4 per lane.
// ============================================================================
__global__ void scatter_edges(const float* __restrict__ X,
                              const int* __restrict__ src, const int* __restrict__ dst,
                              const float* __restrict__ ew,
                              float* __restrict__ agg, float* __restrict__ deg, int E)
{
    int t = blockIdx.x * blockDim.x + threadIdx.x;
    int e = t >> 5;
    if (e >= E) return;
    int lane = t & 31;
    int s  = src[e];
    int dd = dst[e];
    float w = ew ? ew[e] : 1.0f;
    float4 v = *reinterpret_cast<const float4*>(X + (size_t)s * D + lane * 4);
    float* ap = agg + (size_t)dd * D + lane * 4;
    atomicAdd(ap + 0, v.x * w);
    atomicAdd(ap + 1, v.y * w);
    atomicAdd(ap + 2, v.z * w);
    atomicAdd(ap + 3, v.w * w);
    if (lane == 0) atomicAdd(deg + dd, 1.0f);
}

// agg[row] *= 1 / max(deg[row], 1)
__global__ void normalize_rows(float* __restrict__ agg, const float* __restrict__ deg, int n)
{
    int t = blockIdx.x * blockDim.x + threadIdx.x;
    if (t >= n * 32) return;
    int row = t >> 5;
    float r = 1.0f / fmaxf(deg[row], 1.0f);
    float4* p = reinterpret_cast<float4*>(agg) + t;
    float4 v = *p;
    v.x *= r; v.y *= r; v.z *= r; v.w *= r;
    *p = v;
}

// ============================================================================
// Weight folding:  S1f = W2 @ S1, N1f = W2 @ N1, b1f = W2 @ b1 + w2_b
//                  T1f = W3 @ T1, U1f = W3 @ U1, e1f = W3 @ e1 + w3_b
// (lets the layer-1 SAGE output + following projection run as ONE GEMM pass)
// ============================================================================
__global__ void fold_weights(const float* __restrict__ w2_W, const float* __restrict__ w2_b,
                             const float* __restrict__ S1, const float* __restrict__ N1,
                             const float* __restrict__ b1,
                             const float* __restrict__ w3_W, const float* __restrict__ w3_b,
                             const float* __restrict__ T1, const float* __restrict__ U1,
                             const float* __restrict__ e1,
                             float* __restrict__ S1f, float* __restrict__ N1f, float* __restrict__ b1f,
                             float* __restrict__ T1f, float* __restrict__ U1f, float* __restrict__ e1f)
{
    int b = blockIdx.x;
    int tid = threadIdx.x;
    if (b < 256) {
        int m = b >> 6;                       // 0..3: which matrix
        const float* WA = (m < 2) ? w2_W : w3_W;
        const float* SB = (m == 0) ? S1 : (m == 1) ? N1 : (m == 2) ? T1 : U1;
        float* O        = (m == 0) ? S1f : (m == 1) ? N1f : (m == 2) ? T1f : U1f;
        int elem = (b & 63) * 256 + tid;      // 0..16383
        int i = elem >> 7;
        int k = elem & 127;
        float sum = 0.f;
        for (int j = 0; j < 128; ++j)
            sum = fmaf(WA[i * 128 + j], SB[j * 128 + k], sum);
        O[elem] = sum;
    } else if (b == 256) {
        if (tid < 128) {
            float sum = w2_b[tid];
            for (int j = 0; j < 128; ++j) sum = fmaf(w2_W[tid * 128 + j], b1[j], sum);
            b1f[tid] = sum;
        }
    } else {
        if (tid < 128) {
            float sum = w3_b[tid];
            for (int j = 0; j < 128; ++j) sum = fmaf(w3_W[tid * 128 + j], e1[j], sum);
            e1f[tid] = sum;
        }
    }
}

// ============================================================================
extern "C" void kernel_launch(void* const* d_in, const int* in_sizes, int n_in,
                              void* d_out, int out_size, void* d_ws, size_t ws_size,
                              hipStream_t stream)
{
    const float* ii      = (const float*)d_in[0];
    const float* e_emb   = (const float*)d_in[1];
    const float* kemb    = (const float*)d_in[2];
    const float* cf_ew   = (const float*)d_in[3];
    const int*   b_src   = (const int*)d_in[4];
    const int*   b_dst   = (const int*)d_in[5];
    const int*   c_src   = (const int*)d_in[6];
    const int*   c_dst   = (const int*)d_in[7];
    const float* ek_self = (const float*)d_in[8];
    const float* ek_neigh= (const float*)d_in[9];
    const float* ek_bias = (const float*)d_in[10];
    const float* ee_self = (const float*)d_in[11];
    const float* ee_neigh= (const float*)d_in[12];
    const float* ee_bias = (const float*)d_in[13];
    const float* w1_W    = (const float*)d_in[14];
    const float* w1_b    = (const float*)d_in[15];
    const float* w2_W    = (const float*)d_in[16];
    const float* w2_b    = (const float*)d_in[17];
    const float* w3_W    = (const float*)d_in[18];
    const float* w3_b    = (const float*)d_in[19];
    const float* w4_W    = (const float*)d_in[20];
    const float* w4_b    = (const float*)d_in[21];
    const float* comb_W  = (const float*)d_in[22];
    const float* comb_b  = (const float*)d_in[23];

    const int n_k = in_sizes[0] / D;    // 10000
    const int n_e = in_sizes[1] / D;    // 100000
    const int E   = in_sizes[4];        // 1600000

    // ---- workspace layout (~108 MB) ----
    char* wsb = (char*)d_ws;
    const size_t rowBytes = (size_t)n_e * D * sizeof(float);          // 51.2 MB
    const size_t degBytes = (((size_t)n_e * 4) + 255) / 256 * 256;
    float* A   = (float*)wsb;  wsb += rowBytes;     // dst1 / src_com / dst1c
    float* AGG = (float*)wsb;  wsb += rowBytes;     // agg -> neigh -> h_iS
    float* DEG = (float*)wsb;  wsb += degBytes;     // contiguous after AGG
    float* II2 = (float*)wsb;  wsb += (size_t)n_k * D * sizeof(float);
    float* S1f = (float*)wsb;  wsb += D * D * sizeof(float);
    float* N1f = (float*)wsb;  wsb += D * D * sizeof(float);
    float* T1f = (float*)wsb;  wsb += D * D * sizeof(float);
    float* U1f = (float*)wsb;  wsb += D * D * sizeof(float);
    float* b1f = (float*)wsb;  wsb += 256;
    float* e1f = (float*)wsb;  wsb += 256;
    float* OUT = (float*)d_out;                     // also holds h_iI

    const int gemmGridE = (n_e + 63) / 64;          // 1563
    const int gemmGridK = (n_k + 63) / 64;          // 157
    const int scatGrid  = (E * 32 + 255) / 256;     // 200000
    const int normGrid  = (n_e * 32 + 255) / 256;   // 12500

    // 0) fold layer-1 weights through w2 / w3
    fold_weights<<<258, 256, 0, stream>>>(w2_W, w2_b,
        ek_self + D*D, ek_neigh + D*D, ek_bias + D,
        w3_W, w3_b,
        ee_self + D*D, ee_neigh + D*D, ee_bias + D,
        S1f, N1f, b1f, T1f, U1f, e1f);

    // 1) ii2 = [ii ; kemb] @ w4^T + b4
    gemm_dual<0, true><<<gemmGridK, 256, 0, stream>>>(
        ii, w4_W, 2*D, kemb, w4_W + D, 2*D, w4_b, II2, n_k);

    // 2) belong aggregation (mean of ii2 over incoming edges)
    hipMemsetAsync(AGG, 0, rowBytes + degBytes, stream);
    scatter_edges<<<scatGrid, 256, 0, stream>>>(II2, b_src, b_dst, nullptr, AGG, DEG, E);
    normalize_rows<<<normGrid, 256, 0, stream>>>(AGG, DEG, n_e);

    // 3) dst1 = relu(e_emb@S0^T + neigh@N0^T + b0)
    gemm_dual<1, true><<<gemmGridE, 256, 0, stream>>>(
        e_emb, ek_self, D, AGG, ek_neigh, D, ek_bias, A, n_e);

    // 4) h_iI = dst1@S1f^T + neigh@N1f^T + b1f   (w2 folded in) -> d_out
    gemm_dual<0, true><<<gemmGridE, 256, 0, stream>>>(
        A, S1f, D, AGG, N1f, D, b1f, OUT, n_e);

    // 5) src_com = [h_iI ; e_emb] @ w1^T + b1 -> A
    gemm_dual<0, true><<<gemmGridE, 256, 0, stream>>>(
        OUT, w1_W, 2*D, e_emb, w1_W + D, 2*D, w1_b, A, n_e);

    // 6) collab aggregation (edge-weighted mean of src_com)
    hipMemsetAsync(AGG, 0, rowBytes + degBytes, stream);
    scatter_edges<<<scatGrid, 256, 0, stream>>>(A, c_src, c_dst, cf_ew, AGG, DEG, E);
    normalize_rows<<<normGrid, 256, 0, stream>>>(AGG, DEG, n_e);

    // 7) dst1c = relu(e_emb@T0^T + neigh_c@U0^T + eb0) -> A (src_com dead)
    gemm_dual<1, true><<<gemmGridE, 256, 0, stream>>>(
        e_emb, ee_self, D, AGG, ee_neigh, D, ee_bias, A, n_e);

    // 8) h_iS = dst1c@T1f^T + neigh_c@U1f^T + e1f  (w3 folded) -> AGG in place
    gemm_dual<0, true><<<gemmGridE, 256, 0, stream>>>(
        A, T1f, D, AGG, U1f, D, e1f, AGG, n_e);

    // 9) out = leaky( [h_iI ; h_iS] @ comb^T + cb ), in place over h_iI
    gemm_dual<2, true><<<gemmGridE, 256, 0, stream>>>(
        OUT, comb_W, 2*D, AGG, comb_W + D, 2*D, comb_b, OUT, n_e);
}

// Round 4
// 1571.473 us; speedup vs baseline: 4.1369x; 4.1369x over previous
//
#include <hip/hip_runtime.h>

#define D 128

// ============================================================================
// Fused dual-source GEMM:  out[M][128] = act( X1 @ W1^T + X2 @ W2^T + bias )
//   ACT: 0 = none, 1 = relu, 2 = leaky(0.2)
//   Safe for out == X1 / out == X2 (tiles fully staged before epilogue write).
// ============================================================================
template<int ACT, bool DUAL>
__global__ __launch_bounds__(256, 2)
void gemm_dual(const float* __restrict__ X1, const float* __restrict__ W1, int ws1,
               const float* __restrict__ X2, const float* __restrict__ W2, int ws2,
               const float* __restrict__ bias, float* __restrict__ out, int M)
{
    __shared__ float sXT[D][68];    // X^T tile: [k][r], 64 rows, pad 68
    __shared__ float sWT[64][132];  // W^T half: [k - kh*64][c], pad 132
    const int tid  = threadIdx.x;
    const int row0 = blockIdx.x * 64;
    const int c0 = (tid & 31) * 4;   // 4 output cols
    const int r0 = (tid >> 5) * 8;   // 8 output rows
    float acc[8][4] = {};

    #pragma unroll
    for (int s = 0; s < (DUAL ? 2 : 1); ++s) {
        const float* __restrict__ X = s ? X2 : X1;
        const float* __restrict__ W = s ? W2 : W1;
        const int ws = s ? ws2 : ws1;
        __syncthreads();   // protect sXT against readers from previous source
        #pragma unroll
        for (int i = 0; i < 8; ++i) {
            int idx = tid + i * 256;
            int r  = idx >> 5;
            int kq = idx & 31;
            float4 v = make_float4(0.f, 0.f, 0.f, 0.f);
            int gr = row0 + r;
            if (gr < M) v = *reinterpret_cast<const float4*>(X + (size_t)gr * D + kq * 4);
            sXT[kq*4+0][r] = v.x;
            sXT[kq*4+1][r] = v.y;
            sXT[kq*4+2][r] = v.z;
            sXT[kq*4+3][r] = v.w;
        }
        for (int kh = 0; kh < 2; ++kh) {
            __syncthreads();
            {
                int c   = tid >> 1;
                int kkb = (tid & 1) * 32;
                const float* wr = W + (size_t)c * ws + kh * 64 + kkb;
                #pragma unroll
                for (int j = 0; j < 8; ++j) {
                    float4 v = *reinterpret_cast<const float4*>(wr + j * 4);
                    sWT[kkb + j*4 + 0][c] = v.x;
                    sWT[kkb + j*4 + 1][c] = v.y;
                    sWT[kkb + j*4 + 2][c] = v.z;
                    sWT[kkb + j*4 + 3][c] = v.w;
                }
            }
            __syncthreads();
            #pragma unroll 8
            for (int kk = 0; kk < 64; ++kk) {
                const int k = kh * 64 + kk;
                const float4 a0 = *reinterpret_cast<const float4*>(&sXT[k][r0]);
                const float4 a1 = *reinterpret_cast<const float4*>(&sXT[k][r0 + 4]);
                const float4 w  = *reinterpret_cast<const float4*>(&sWT[kk][c0]);
                const float av[8] = {a0.x, a0.y, a0.z, a0.w, a1.x, a1.y, a1.z, a1.w};
                #pragma unroll
                for (int j = 0; j < 8; ++j) {
                    acc[j][0] = fmaf(av[j], w.x, acc[j][0]);
                    acc[j][1] = fmaf(av[j], w.y, acc[j][1]);
                    acc[j][2] = fmaf(av[j], w.z, acc[j][2]);
                    acc[j][3] = fmaf(av[j], w.w, acc[j][3]);
                }
            }
        }
    }
    const float4 bv = *reinterpret_cast<const float4*>(bias + c0);
    #pragma unroll
    for (int j = 0; j < 8; ++j) {
        int gr = row0 + r0 + j;
        if (gr < M) {
            float4 o;
            o.x = acc[j][0] + bv.x;
            o.y = acc[j][1] + bv.y;
            o.z = acc[j][2] + bv.z;
            o.w = acc[j][3] + bv.w;
            if (ACT == 1) {
                o.x = fmaxf(o.x, 0.f); o.y = fmaxf(o.y, 0.f);
                o.z = fmaxf(o.z, 0.f); o.w = fmaxf(o.w, 0.f);
            } else if (ACT == 2) {
                o.x = o.x >= 0.f ? o.x : 0.2f * o.x;
                o.y = o.y >= 0.f ? o.y : 0.2f * o.y;
                o.z = o.z >= 0.f ? o.z : 0.2f * o.z;
                o.w = o.w >= 0.f ? o.w : 0.2f * o.w;
            }
            *reinterpret_cast<float4*>(out + (size_t)gr * D + c0) = o;
        }
    }
}

// ============================================================================
// CSR build: histogram -> exclusive scan -> fill (counting sort by dst)
// ============================================================================
__global__ void hist_dst(const int* __restrict__ dst, int* __restrict__ cnt, int E)
{
    int e = blockIdx.x * blockDim.x + threadIdx.x;
    if (e < E) atomicAdd(&cnt[dst[e]], 1);
}

// per-block partial sums over 1024-element chunks
__global__ void scan_sums(const int* __restrict__ cnt, int* __restrict__ bsums, int n)
{
    __shared__ int sdata[256];
    int base = blockIdx.x * 1024;
    int t = threadIdx.x;
    int s = 0;
    #pragma unroll
    for (int j = 0; j < 4; ++j) {
        int i = base + t * 4 + j;
        if (i < n) s += cnt[i];
    }
    sdata[t] = s;
    __syncthreads();
    for (int off = 128; off > 0; off >>= 1) {
        if (t < off) sdata[t] += sdata[t + off];
        __syncthreads();
    }
    if (t == 0) bsums[blockIdx.x] = sdata[0];
}

__global__ void scan_bsums(int* __restrict__ bsums, int nb)
{
    if (blockIdx.x == 0 && threadIdx.x == 0) {
        int run = 0;
        for (int i = 0; i < nb; ++i) { int v = bsums[i]; bsums[i] = run; run += v; }
    }
}

__global__ void scan_apply(const int* __restrict__ cnt, const int* __restrict__ bsums,
                           int* __restrict__ rowptr, int* __restrict__ cursor, int n, int E)
{
    __shared__ int sthread[256];
    int base = blockIdx.x * 1024;
    int t = threadIdx.x;
    int vals[4]; int s = 0;
    #pragma unroll
    for (int j = 0; j < 4; ++j) {
        int i = base + t * 4 + j;
        vals[j] = (i < n) ? cnt[i] : 0;
        s += vals[j];
    }
    sthread[t] = s;
    __syncthreads();
    int pre = 0;
    for (int i = 0; i < t; ++i) pre += sthread[i];   // n is tiny; naive scan is fine
    pre += bsums[blockIdx.x];
    #pragma unroll
    for (int j = 0; j < 4; ++j) {
        int i = base + t * 4 + j;
        if (i < n) { rowptr[i] = pre; cursor[i] = pre; pre += vals[j]; }
    }
    if (blockIdx.x == 0 && t == 0) rowptr[n] = E;
}

__global__ void fill_csr(const int* __restrict__ src, const int* __restrict__ dst,
                         const float* __restrict__ ew,
                         int* __restrict__ cursor, int* __restrict__ srcs,
                         float* __restrict__ wsrt, int E)
{
    int e = blockIdx.x * blockDim.x + threadIdx.x;
    if (e >= E) return;
    int p = atomicAdd(&cursor[dst[e]], 1);
    srcs[p] = src[e];
    wsrt[p] = ew ? ew[e] : 1.0f;
}

// ============================================================================
// Gather-side mean: one 64-lane wave per dst node; acc in regs, write row once.
// agg[node] = (1/max(deg,1)) * sum_e w[e] * X[srcs[e]]
// ============================================================================
__global__ __launch_bounds__(256)
void gather_mean(const float* __restrict__ X, const int* __restrict__ rowptr,
                 const int* __restrict__ srcs, const float* __restrict__ wsrt,
                 float* __restrict__ agg, int n)
{
    int t = blockIdx.x * blockDim.x + threadIdx.x;
    int node = t >> 6;
    if (node >= n) return;
    int lane = t & 63;
    int beg = rowptr[node], end = rowptr[node + 1];
    float2 acc = make_float2(0.f, 0.f);
    for (int e = beg; e < end; ++e) {
        int s  = srcs[e];
        float w = wsrt[e];
        float2 v = *reinterpret_cast<const float2*>(X + (size_t)s * D + lane * 2);
        acc.x = fmaf(v.x, w, acc.x);
        acc.y = fmaf(v.y, w, acc.y);
    }
    float inv = 1.0f / fmaxf((float)(end - beg), 1.0f);
    *reinterpret_cast<float2*>(agg + (size_t)node * D + lane * 2) =
        make_float2(acc.x * inv, acc.y * inv);
}

// ============================================================================
// Weight folding:  S1f = W2 @ S1, N1f = W2 @ N1, b1f = W2 @ b1 + w2_b
//                  T1f = W3 @ T1, U1f = W3 @ U1, e1f = W3 @ e1 + w3_b
// ============================================================================
__global__ void fold_weights(const float* __restrict__ w2_W, const float* __restrict__ w2_b,
                             const float* __restrict__ S1, const float* __restrict__ N1,
                             const float* __restrict__ b1,
                             const float* __restrict__ w3_W, const float* __restrict__ w3_b,
                             const float* __restrict__ T1, const float* __restrict__ U1,
                             const float* __restrict__ e1,
                             float* __restrict__ S1f, float* __restrict__ N1f, float* __restrict__ b1f,
                             float* __restrict__ T1f, float* __restrict__ U1f, float* __restrict__ e1f)
{
    int b = blockIdx.x;
    int tid = threadIdx.x;
    if (b < 256) {
        int m = b >> 6;
        const float* WA = (m < 2) ? w2_W : w3_W;
        const float* SB = (m == 0) ? S1 : (m == 1) ? N1 : (m == 2) ? T1 : U1;
        float* O        = (m == 0) ? S1f : (m == 1) ? N1f : (m == 2) ? T1f : U1f;
        int elem = (b & 63) * 256 + tid;
        int i = elem >> 7;
        int k = elem & 127;
        float sum = 0.f;
        for (int j = 0; j < 128; ++j)
            sum = fmaf(WA[i * 128 + j], SB[j * 128 + k], sum);
        O[elem] = sum;
    } else if (b == 256) {
        if (tid < 128) {
            float sum = w2_b[tid];
            for (int j = 0; j < 128; ++j) sum = fmaf(w2_W[tid * 128 + j], b1[j], sum);
            b1f[tid] = sum;
        }
    } else {
        if (tid < 128) {
            float sum = w3_b[tid];
            for (int j = 0; j < 128; ++j) sum = fmaf(w3_W[tid * 128 + j], e1[j], sum);
            e1f[tid] = sum;
        }
    }
}

// ============================================================================
extern "C" void kernel_launch(void* const* d_in, const int* in_sizes, int n_in,
                              void* d_out, int out_size, void* d_ws, size_t ws_size,
                              hipStream_t stream)
{
    const float* ii      = (const float*)d_in[0];
    const float* e_emb   = (const float*)d_in[1];
    const float* kemb    = (const float*)d_in[2];
    const float* cf_ew   = (const float*)d_in[3];
    const int*   b_src   = (const int*)d_in[4];
    const int*   b_dst   = (const int*)d_in[5];
    const int*   c_src   = (const int*)d_in[6];
    const int*   c_dst   = (const int*)d_in[7];
    const float* ek_self = (const float*)d_in[8];
    const float* ek_neigh= (const float*)d_in[9];
    const float* ek_bias = (const float*)d_in[10];
    const float* ee_self = (const float*)d_in[11];
    const float* ee_neigh= (const float*)d_in[12];
    const float* ee_bias = (const float*)d_in[13];
    const float* w1_W    = (const float*)d_in[14];
    const float* w1_b    = (const float*)d_in[15];
    const float* w2_W    = (const float*)d_in[16];
    const float* w2_b    = (const float*)d_in[17];
    const float* w3_W    = (const float*)d_in[18];
    const float* w3_b    = (const float*)d_in[19];
    const float* w4_W    = (const float*)d_in[20];
    const float* w4_b    = (const float*)d_in[21];
    const float* comb_W  = (const float*)d_in[22];
    const float* comb_b  = (const float*)d_in[23];

    const int n_k = in_sizes[0] / D;    // 10000
    const int n_e = in_sizes[1] / D;    // 100000
    const int E   = in_sizes[4];        // 1600000

    // ---- workspace layout (~122 MB) ----
    char* wsb = (char*)d_ws;
    const size_t rowBytes = (size_t)n_e * D * sizeof(float);          // 51.2 MB
    auto align256 = [](size_t x) { return (x + 255) & ~(size_t)255; };
    float* A      = (float*)wsb;  wsb += rowBytes;                    // dst1 / src_com / dst1c
    float* AGG    = (float*)wsb;  wsb += rowBytes;                    // neigh -> h_iS
    float* II2    = (float*)wsb;  wsb += align256((size_t)n_k * D * sizeof(float));
    int*   rowptr = (int*)wsb;    wsb += align256((size_t)(n_e + 1) * sizeof(int));
    int*   cursor = (int*)wsb;    wsb += align256((size_t)n_e * sizeof(int));
    int*   srcs   = (int*)wsb;    wsb += align256((size_t)E * sizeof(int));
    float* wsrt   = (float*)wsb;  wsb += align256((size_t)E * sizeof(float));
    int*   bsums  = (int*)wsb;    wsb += 4096;
    float* S1f    = (float*)wsb;  wsb += D * D * sizeof(float);
    float* N1f    = (float*)wsb;  wsb += D * D * sizeof(float);
    float* T1f    = (float*)wsb;  wsb += D * D * sizeof(float);
    float* U1f    = (float*)wsb;  wsb += D * D * sizeof(float);
    float* b1f    = (float*)wsb;  wsb += 256;
    float* e1f    = (float*)wsb;  wsb += 256;
    float* OUT    = (float*)d_out;                                    // also holds h_iI

    const int gemmGridE = (n_e + 63) / 64;
    const int gemmGridK = (n_k + 63) / 64;
    const int edgeGrid  = (E + 255) / 256;
    const int scanNB    = (n_e + 1023) / 1024;        // 98
    const int gathGrid  = (n_e * 64 + 255) / 256;     // 25000

    // 0) fold layer-1 weights through w2 / w3
    fold_weights<<<258, 256, 0, stream>>>(w2_W, w2_b,
        ek_self + D*D, ek_neigh + D*D, ek_bias + D,
        w3_W, w3_b,
        ee_self + D*D, ee_neigh + D*D, ee_bias + D,
        S1f, N1f, b1f, T1f, U1f, e1f);

    // 1) ii2 = [ii ; kemb] @ w4^T + b4
    gemm_dual<0, true><<<gemmGridK, 256, 0, stream>>>(
        ii, w4_W, 2*D, kemb, w4_W + D, 2*D, w4_b, II2, n_k);

    // 2) belong graph: CSR build + gather mean of II2
    hipMemsetAsync(cursor, 0, (size_t)n_e * sizeof(int), stream);
    hist_dst<<<edgeGrid, 256, 0, stream>>>(b_dst, cursor, E);
    scan_sums<<<scanNB, 256, 0, stream>>>(cursor, bsums, n_e);
    scan_bsums<<<1, 64, 0, stream>>>(bsums, scanNB);
    scan_apply<<<scanNB, 256, 0, stream>>>(cursor, bsums, rowptr, cursor, n_e, E);
    fill_csr<<<edgeGrid, 256, 0, stream>>>(b_src, b_dst, nullptr, cursor, srcs, wsrt, E);
    gather_mean<<<gathGrid, 256, 0, stream>>>(II2, rowptr, srcs, wsrt, AGG, n_e);

    // 3) dst1 = relu(e_emb@S0^T + neigh@N0^T + b0)
    gemm_dual<1, true><<<gemmGridE, 256, 0, stream>>>(
        e_emb, ek_self, D, AGG, ek_neigh, D, ek_bias, A, n_e);

    // 4) h_iI = dst1@S1f^T + neigh@N1f^T + b1f   (w2 folded in) -> d_out
    gemm_dual<0, true><<<gemmGridE, 256, 0, stream>>>(
        A, S1f, D, AGG, N1f, D, b1f, OUT, n_e);

    // 5) src_com = [h_iI ; e_emb] @ w1^T + b1 -> A
    gemm_dual<0, true><<<gemmGridE, 256, 0, stream>>>(
        OUT, w1_W, 2*D, e_emb, w1_W + D, 2*D, w1_b, A, n_e);

    // 6) collab graph: CSR build + edge-weighted gather mean of src_com
    hipMemsetAsync(cursor, 0, (size_t)n_e * sizeof(int), stream);
    hist_dst<<<edgeGrid, 256, 0, stream>>>(c_dst, cursor, E);
    scan_sums<<<scanNB, 256, 0, stream>>>(cursor, bsums, n_e);
    scan_bsums<<<1, 64, 0, stream>>>(bsums, scanNB);
    scan_apply<<<scanNB, 256, 0, stream>>>(cursor, bsums, rowptr, cursor, n_e, E);
    fill_csr<<<edgeGrid, 256, 0, stream>>>(c_src, c_dst, cf_ew, cursor, srcs, wsrt, E);
    gather_mean<<<gathGrid, 256, 0, stream>>>(A, rowptr, srcs, wsrt, AGG, n_e);

    // 7) dst1c = relu(e_emb@T0^T + neigh_c@U0^T + eb0) -> A (src_com dead)
    gemm_dual<1, true><<<gemmGridE, 256, 0, stream>>>(
        e_emb, ee_self, D, AGG, ee_neigh, D, ee_bias, A, n_e);

    // 8) h_iS = dst1c@T1f^T + neigh_c@U1f^T + e1f  (w3 folded) -> AGG in place
    gemm_dual<0, true><<<gemmGridE, 256, 0, stream>>>(
        A, T1f, D, AGG, U1f, D, e1f, AGG, n_e);

    // 9) out = leaky( [h_iI ; h_iS] @ comb^T + cb ), in place over h_iI
    gemm_dual<2, true><<<gemmGridE, 256, 0, stream>>>(
        OUT, comb_W, 2*D, AGG, comb_W + D, 2*D, comb_b, OUT, n_e);
}

// Round 7
// 1039.818 us; speedup vs baseline: 6.2521x; 1.5113x over previous
//
#include <hip/hip_runtime.h>

#define D 128

using f16   = _Float16;
using f16x4 = __attribute__((ext_vector_type(4))) _Float16;
using f16x8 = __attribute__((ext_vector_type(8))) _Float16;
using f32x4 = __attribute__((ext_vector_type(4))) float;

// ============================================================================
// Fused dual-source MFMA GEMM: out[M][128] = act( X1 @ W1^T + X2 @ W2^T + b )
//   fp16 inputs (converted at staging), f32 accumulate.
//   Block: 256 thr = 4 waves, 64 rows x 128 cols. Wave w: rows [w*16, w*16+16).
//   mfma_f32_16x16x32_f16: A lane l holds A[l&15][(l>>4)*8 + j];
//                          B lane l holds B[(l>>4)*8 + j][l&15];
//                          C lane l reg r -> row (l>>4)*4+r, col l&15 (m89).
//   Safe for out == X1 / out == X2 (epilogue after all staging; own rows only).
// ============================================================================
template<int ACT>
__global__ __launch_bounds__(256, 3)
void gemm_dual_mfma(const float* __restrict__ X1, const float* __restrict__ W1, int ws1,
                    const float* __restrict__ X2, const float* __restrict__ W2, int ws2,
                    const float* __restrict__ bias, float* __restrict__ out, int M)
{
    __shared__ f16 sX[64][136];    // 64 rows x 128 k, +8 pad (even bank spread)
    __shared__ f16 sW[128][136];   // 128 out-cols x 128 k, +8 pad
    const int tid  = threadIdx.x;
    const int row0 = blockIdx.x * 64;
    const int wave = tid >> 6;
    const int lane = tid & 63;
    const int lm   = lane & 15;    // A row / B col / C col
    const int lg   = lane >> 4;    // k-group / C row-group

    f32x4 acc[8];
    #pragma unroll
    for (int i = 0; i < 8; ++i) acc[i] = (f32x4){0.f, 0.f, 0.f, 0.f};

    for (int s = 0; s < 2; ++s) {
        const float* __restrict__ X = s ? X2 : X1;
        const float* __restrict__ W = s ? W2 : W1;
        const int ws = s ? ws2 : ws1;
        __syncthreads();   // previous source's compute done before restage
        // ---- stage X tile (64 x 128) ----
        #pragma unroll
        for (int i = 0; i < 8; ++i) {
            int idx = i * 256 + tid;
            int r   = idx >> 5;
            int kq  = idx & 31;
            float4 v = make_float4(0.f, 0.f, 0.f, 0.f);
            int gr = row0 + r;
            if (gr < M) v = *reinterpret_cast<const float4*>(X + (size_t)gr * D + kq * 4);
            f16x4 h; h[0] = (f16)v.x; h[1] = (f16)v.y; h[2] = (f16)v.z; h[3] = (f16)v.w;
            *reinterpret_cast<f16x4*>(&sX[r][kq * 4]) = h;
        }
        // ---- stage W tile (128 x 128) ----
        #pragma unroll
        for (int i = 0; i < 16; ++i) {
            int idx = i * 256 + tid;
            int c   = idx >> 5;
            int kq  = idx & 31;
            float4 v = *reinterpret_cast<const float4*>(W + (size_t)c * ws + kq * 4);
            f16x4 h; h[0] = (f16)v.x; h[1] = (f16)v.y; h[2] = (f16)v.z; h[3] = (f16)v.w;
            *reinterpret_cast<f16x4*>(&sW[c][kq * 4]) = h;
        }
        __syncthreads();
        // ---- MFMA: 4 k-steps x 8 n-tiles ----
        #pragma unroll
        for (int ks = 0; ks < 4; ++ks) {
            f16x8 a = *reinterpret_cast<const f16x8*>(&sX[wave * 16 + lm][ks * 32 + lg * 8]);
            #pragma unroll
            for (int n0 = 0; n0 < 8; ++n0) {
                f16x8 b = *reinterpret_cast<const f16x8*>(&sW[n0 * 16 + lm][ks * 32 + lg * 8]);
                acc[n0] = __builtin_amdgcn_mfma_f32_16x16x32_f16(a, b, acc[n0], 0, 0, 0);
            }
        }
    }
    // ---- epilogue: bias + act + store ----
    #pragma unroll
    for (int n0 = 0; n0 < 8; ++n0) {
        int col = n0 * 16 + lm;
        float bv = bias[col];
        #pragma unroll
        for (int r = 0; r < 4; ++r) {
            int row = row0 + wave * 16 + lg * 4 + r;
            if (row < M) {
                float o = acc[n0][r] + bv;
                if (ACT == 1) o = fmaxf(o, 0.f);
                else if (ACT == 2) o = o >= 0.f ? o : 0.2f * o;
                out[(size_t)row * D + col] = o;
            }
        }
    }
}

// ============================================================================
// CSR build: histogram -> exclusive scan -> fill (counting sort by dst)
// ============================================================================
__global__ void hist_dst(const int* __restrict__ dst, int* __restrict__ cnt, int E)
{
    int e = blockIdx.x * blockDim.x + threadIdx.x;
    if (e < E) atomicAdd(&cnt[dst[e]], 1);
}

__global__ void scan_sums(const int* __restrict__ cnt, int* __restrict__ bsums, int n)
{
    __shared__ int sdata[256];
    int base = blockIdx.x * 1024;
    int t = threadIdx.x;
    int s = 0;
    #pragma unroll
    for (int j = 0; j < 4; ++j) {
        int i = base + t * 4 + j;
        if (i < n) s += cnt[i];
    }
    sdata[t] = s;
    __syncthreads();
    for (int off = 128; off > 0; off >>= 1) {
        if (t < off) sdata[t] += sdata[t + off];
        __syncthreads();
    }
    if (t == 0) bsums[blockIdx.x] = sdata[0];
}

__global__ void scan_bsums(int* __restrict__ bsums, int nb)
{
    if (blockIdx.x == 0 && threadIdx.x == 0) {
        int run = 0;
        for (int i = 0; i < nb; ++i) { int v = bsums[i]; bsums[i] = run; run += v; }
    }
}

__global__ void scan_apply(const int* __restrict__ cnt, const int* __restrict__ bsums,
                           int* __restrict__ rowptr, int* __restrict__ cursor, int n, int E)
{
    __shared__ int sthread[256];
    int base = blockIdx.x * 1024;
    int t = threadIdx.x;
    int vals[4]; int s = 0;
    #pragma unroll
    for (int j = 0; j < 4; ++j) {
        int i = base + t * 4 + j;
        vals[j] = (i < n) ? cnt[i] : 0;
        s += vals[j];
    }
    sthread[t] = s;
    __syncthreads();
    int pre = 0;
    for (int i = 0; i < t; ++i) pre += sthread[i];
    pre += bsums[blockIdx.x];
    #pragma unroll
    for (int j = 0; j < 4; ++j) {
        int i = base + t * 4 + j;
        if (i < n) { rowptr[i] = pre; cursor[i] = pre; pre += vals[j]; }
    }
    if (blockIdx.x == 0 && t == 0) rowptr[n] = E;
}

__global__ void fill_csr(const int* __restrict__ src, const int* __restrict__ dst,
                         const float* __restrict__ ew,
                         int* __restrict__ cursor, int* __restrict__ srcs,
                         float* __restrict__ wsrt, int E)
{
    int e = blockIdx.x * blockDim.x + threadIdx.x;
    if (e >= E) return;
    int p = atomicAdd(&cursor[dst[e]], 1);
    srcs[p] = src[e];
    wsrt[p] = ew ? ew[e] : 1.0f;
}

// ============================================================================
// Gather-side mean: one 64-lane wave per dst node; 2 edges in flight
// (half-wave h handles edge beg+2i+h with 32 lanes x float4 = full 512 B row).
// ============================================================================
__global__ __launch_bounds__(256)
void gather_mean(const float* __restrict__ X, const int* __restrict__ rowptr,
                 const int* __restrict__ srcs, const float* __restrict__ wsrt,
                 float* __restrict__ agg, int n)
{
    int t = blockIdx.x * blockDim.x + threadIdx.x;
    int node = t >> 6;
    if (node >= n) return;
    int lane = t & 63;
    int h = lane >> 5;
    int q = lane & 31;
    int beg = rowptr[node], end = rowptr[node + 1];
    float4 acc = make_float4(0.f, 0.f, 0.f, 0.f);
    for (int e = beg + h; e < end; e += 2) {
        int s  = srcs[e];
        float w = wsrt[e];
        float4 v = *reinterpret_cast<const float4*>(X + (size_t)s * D + q * 4);
        acc.x = fmaf(v.x, w, acc.x);
        acc.y = fmaf(v.y, w, acc.y);
        acc.z = fmaf(v.z, w, acc.z);
        acc.w = fmaf(v.w, w, acc.w);
    }
    acc.x += __shfl_xor(acc.x, 32);
    acc.y += __shfl_xor(acc.y, 32);
    acc.z += __shfl_xor(acc.z, 32);
    acc.w += __shfl_xor(acc.w, 32);
    if (h == 0) {
        float inv = 1.0f / fmaxf((float)(end - beg), 1.0f);
        *reinterpret_cast<float4*>(agg + (size_t)node * D + q * 4) =
            make_float4(acc.x * inv, acc.y * inv, acc.z * inv, acc.w * inv);
    }
}

// ============================================================================
// Weight folding:  S1f = W2 @ S1, N1f = W2 @ N1, b1f = W2 @ b1 + w2_b
//                  T1f = W3 @ T1, U1f = W3 @ U1, e1f = W3 @ e1 + w3_b
// ============================================================================
__global__ void fold_weights(const float* __restrict__ w2_W, const float* __restrict__ w2_b,
                             const float* __restrict__ S1, const float* __restrict__ N1,
                             const float* __restrict__ b1,
                             const float* __restrict__ w3_W, const float* __restrict__ w3_b,
                             const float* __restrict__ T1, const float* __restrict__ U1,
                             const float* __restrict__ e1,
                             float* __restrict__ S1f, float* __restrict__ N1f, float* __restrict__ b1f,
                             float* __restrict__ T1f, float* __restrict__ U1f, float* __restrict__ e1f)
{
    int b = blockIdx.x;
    int tid = threadIdx.x;
    if (b < 256) {
        int m = b >> 6;
        const float* WA = (m < 2) ? w2_W : w3_W;
        const float* SB = (m == 0) ? S1 : (m == 1) ? N1 : (m == 2) ? T1 : U1;
        float* O        = (m == 0) ? S1f : (m == 1) ? N1f : (m == 2) ? T1f : U1f;
        int elem = (b & 63) * 256 + tid;
        int i = elem >> 7;
        int k = elem & 127;
        float sum = 0.f;
        for (int j = 0; j < 128; ++j)
            sum = fmaf(WA[i * 128 + j], SB[j * 128 + k], sum);
        O[elem] = sum;
    } else if (b == 256) {
        if (tid < 128) {
            float sum = w2_b[tid];
            for (int j = 0; j < 128; ++j) sum = fmaf(w2_W[tid * 128 + j], b1[j], sum);
            b1f[tid] = sum;
        }
    } else {
        if (tid < 128) {
            float sum = w3_b[tid];
            for (int j = 0; j < 128; ++j) sum = fmaf(w3_W[tid * 128 + j], e1[j], sum);
            e1f[tid] = sum;
        }
    }
}

// ============================================================================
extern "C" void kernel_launch(void* const* d_in, const int* in_sizes, int n_in,
                              void* d_out, int out_size, void* d_ws, size_t ws_size,
                              hipStream_t stream)
{
    const float* ii      = (const float*)d_in[0];
    const float* e_emb   = (const float*)d_in[1];
    const float* kemb    = (const float*)d_in[2];
    const float* cf_ew   = (const float*)d_in[3];
    const int*   b_src   = (const int*)d_in[4];
    const int*   b_dst   = (const int*)d_in[5];
    const int*   c_src   = (const int*)d_in[6];
    const int*   c_dst   = (const int*)d_in[7];
    const float* ek_self = (const float*)d_in[8];
    const float* ek_neigh= (const float*)d_in[9];
    const float* ek_bias = (const float*)d_in[10];
    const float* ee_self = (const float*)d_in[11];
    const float* ee_neigh= (const float*)d_in[12];
    const float* ee_bias = (const float*)d_in[13];
    const float* w1_W    = (const float*)d_in[14];
    const float* w1_b    = (const float*)d_in[15];
    const float* w2_W    = (const float*)d_in[16];
    const float* w2_b    = (const float*)d_in[17];
    const float* w3_W    = (const float*)d_in[18];
    const float* w3_b    = (const float*)d_in[19];
    const float* w4_W    = (const float*)d_in[20];
    const float* w4_b    = (const float*)d_in[21];
    const float* comb_W  = (const float*)d_in[22];
    const float* comb_b  = (const float*)d_in[23];

    const int n_k = in_sizes[0] / D;    // 10000
    const int n_e = in_sizes[1] / D;    // 100000
    const int E   = in_sizes[4];        // 1600000

    // ---- workspace layout (~122 MB) ----
    char* wsb = (char*)d_ws;
    const size_t rowBytes = (size_t)n_e * D * sizeof(float);          // 51.2 MB
    auto align256 = [](size_t x) { return (x + 255) & ~(size_t)255; };
    float* A      = (float*)wsb;  wsb += rowBytes;                    // dst1 / src_com / dst1c
    float* AGG    = (float*)wsb;  wsb += rowBytes;                    // neigh -> h_iS
    float* II2    = (float*)wsb;  wsb += align256((size_t)n_k * D * sizeof(float));
    int*   rowptr = (int*)wsb;    wsb += align256((size_t)(n_e + 1) * sizeof(int));
    int*   cursor = (int*)wsb;    wsb += align256((size_t)n_e * sizeof(int));
    int*   srcs   = (int*)wsb;    wsb += align256((size_t)E * sizeof(int));
    float* wsrt   = (float*)wsb;  wsb += align256((size_t)E * sizeof(float));
    int*   bsums  = (int*)wsb;    wsb += 4096;
    float* S1f    = (float*)wsb;  wsb += D * D * sizeof(float);
    float* N1f    = (float*)wsb;  wsb += D * D * sizeof(float);
    float* T1f    = (float*)wsb;  wsb += D * D * sizeof(float);
    float* U1f    = (float*)wsb;  wsb += D * D * sizeof(float);
    float* b1f    = (float*)wsb;  wsb += 256;
    float* e1f    = (float*)wsb;  wsb += 256;
    float* OUT    = (float*)d_out;                                    // also holds h_iI

    const int gemmGridE = (n_e + 63) / 64;
    const int gemmGridK = (n_k + 63) / 64;
    const int edgeGrid  = (E + 255) / 256;
    const int scanNB    = (n_e + 1023) / 1024;        // 98
    const int gathGrid  = (n_e * 64 + 255) / 256;     // 25000

    // 0) fold layer-1 weights through w2 / w3
    fold_weights<<<258, 256, 0, stream>>>(w2_W, w2_b,
        ek_self + D*D, ek_neigh + D*D, ek_bias + D,
        w3_W, w3_b,
        ee_self + D*D, ee_neigh + D*D, ee_bias + D,
        S1f, N1f, b1f, T1f, U1f, e1f);

    // 1) ii2 = [ii ; kemb] @ w4^T + b4
    gemm_dual_mfma<0><<<gemmGridK, 256, 0, stream>>>(
        ii, w4_W, 2*D, kemb, w4_W + D, 2*D, w4_b, II2, n_k);

    // 2) belong graph: CSR build + gather mean of II2
    hipMemsetAsync(cursor, 0, (size_t)n_e * sizeof(int), stream);
    hist_dst<<<edgeGrid, 256, 0, stream>>>(b_dst, cursor, E);
    scan_sums<<<scanNB, 256, 0, stream>>>(cursor, bsums, n_e);
    scan_bsums<<<1, 64, 0, stream>>>(bsums, scanNB);
    scan_apply<<<scanNB, 256, 0, stream>>>(cursor, bsums, rowptr, cursor, n_e, E);
    fill_csr<<<edgeGrid, 256, 0, stream>>>(b_src, b_dst, nullptr, cursor, srcs, wsrt, E);
    gather_mean<<<gathGrid, 256, 0, stream>>>(II2, rowptr, srcs, wsrt, AGG, n_e);

    // 3) dst1 = relu(e_emb@S0^T + neigh@N0^T + b0)
    gemm_dual_mfma<1><<<gemmGridE, 256, 0, stream>>>(
        e_emb, ek_self, D, AGG, ek_neigh, D, ek_bias, A, n_e);

    // 4) h_iI = dst1@S1f^T + neigh@N1f^T + b1f   (w2 folded in) -> d_out
    gemm_dual_mfma<0><<<gemmGridE, 256, 0, stream>>>(
        A, S1f, D, AGG, N1f, D, b1f, OUT, n_e);

    // 5) src_com = [h_iI ; e_emb] @ w1^T + b1 -> A
    gemm_dual_mfma<0><<<gemmGridE, 256, 0, stream>>>(
        OUT, w1_W, 2*D, e_emb, w1_W + D, 2*D, w1_b, A, n_e);

    // 6) collab graph: CSR build + edge-weighted gather mean of src_com
    hipMemsetAsync(cursor, 0, (size_t)n_e * sizeof(int), stream);
    hist_dst<<<edgeGrid, 256, 0, stream>>>(c_dst, cursor, E);
    scan_sums<<<scanNB, 256, 0, stream>>>(cursor, bsums, n_e);
    scan_bsums<<<1, 64, 0, stream>>>(bsums, scanNB);
    scan_apply<<<scanNB, 256, 0, stream>>>(cursor, bsums, rowptr, cursor, n_e, E);
    fill_csr<<<edgeGrid, 256, 0, stream>>>(c_src, c_dst, cf_ew, cursor, srcs, wsrt, E);
    gather_mean<<<gathGrid, 256, 0, stream>>>(A, rowptr, srcs, wsrt, AGG, n_e);

    // 7) dst1c = relu(e_emb@T0^T + neigh_c@U0^T + eb0) -> A (src_com dead)
    gemm_dual_mfma<1><<<gemmGridE, 256, 0, stream>>>(
        e_emb, ee_self, D, AGG, ee_neigh, D, ee_bias, A, n_e);

    // 8) h_iS = dst1c@T1f^T + neigh_c@U1f^T + e1f  (w3 folded) -> AGG in place
    gemm_dual_mfma<0><<<gemmGridE, 256, 0, stream>>>(
        A, T1f, D, AGG, U1f, D, e1f, AGG, n_e);

    // 9) out = leaky( [h_iI ; h_iS] @ comb^T + cb ), in place over h_iI
    gemm_dual_mfma<2><<<gemmGridE, 256, 0, stream>>>(
        OUT, comb_W, 2*D, AGG, comb_W + D, 2*D, comb_b, OUT, n_e);
}

// Round 8
// 874.715 us; speedup vs baseline: 7.4322x; 1.1888x over previous
//
#include <hip/hip_runtime.h>

#define D 128

using f16   = _Float16;
using f16x4 = __attribute__((ext_vector_type(4))) _Float16;
using f16x8 = __attribute__((ext_vector_type(8))) _Float16;
using f32x4 = __attribute__((ext_vector_type(4))) float;

__device__ __forceinline__ f16x8 zero8() {
    f16x8 v;
    #pragma unroll
    for (int j = 0; j < 8; ++j) v[j] = (f16)0;
    return v;
}

// ============================================================================
// Fused dual-source MFMA GEMM: out[M][128] = act( X1 @ W1^T + X2 @ W2^T + b )
//   X sources: f16 rows (X?H=true, pure copy staging) or f32 rows (convert).
//   W always f32 (small, L2-hot), converted at staging. f32 accumulate.
//   Output: f16 (O16) or f32. Block: 256 thr = 4 waves, 64 rows x 128 cols.
//   mfma_f32_16x16x32_f16: A lane l holds A[l&15][(l>>4)*8+j]; B same transposed;
//   C lane l reg r -> row (l>>4)*4+r, col l&15  (validated rounds 6-7).
//   In-place safe for out == X1/X2 (block stages its own 64 rows before write).
// ============================================================================
template<bool H>
__device__ __forceinline__ void stage_and_mfma(
    const void* Xv, const float* W, int ws,
    f16 (*sX)[136], f16 (*sW)[136],
    int tid, int row0, int M, int wave, int lm, int lg, f32x4 acc[8])
{
    __syncthreads();   // previous tile consumers done
    if (H) {
        const f16* X = (const f16*)Xv;
        #pragma unroll
        for (int i = 0; i < 4; ++i) {
            int idx = i * 256 + tid;       // 1024 chunks of 8 f16
            int r   = idx >> 4;
            int kc  = idx & 15;
            f16x8 v = zero8();
            int gr = row0 + r;
            if (gr < M) v = *reinterpret_cast<const f16x8*>(X + (size_t)gr * D + kc * 8);
            *reinterpret_cast<f16x8*>(&sX[r][kc * 8]) = v;
        }
    } else {
        const float* X = (const float*)Xv;
        #pragma unroll
        for (int i = 0; i < 8; ++i) {
            int idx = i * 256 + tid;       // 2048 chunks of 4 f32
            int r   = idx >> 5;
            int kq  = idx & 31;
            float4 v = make_float4(0.f, 0.f, 0.f, 0.f);
            int gr = row0 + r;
            if (gr < M) v = *reinterpret_cast<const float4*>(X + (size_t)gr * D + kq * 4);
            f16x4 h; h[0] = (f16)v.x; h[1] = (f16)v.y; h[2] = (f16)v.z; h[3] = (f16)v.w;
            *reinterpret_cast<f16x4*>(&sX[r][kq * 4]) = h;
        }
    }
    // ---- stage W tile (128 x 128, f32 -> f16) ----
    #pragma unroll
    for (int i = 0; i < 16; ++i) {
        int idx = i * 256 + tid;
        int c   = idx >> 5;
        int kq  = idx & 31;
        float4 v = *reinterpret_cast<const float4*>(W + (size_t)c * ws + kq * 4);
        f16x4 h; h[0] = (f16)v.x; h[1] = (f16)v.y; h[2] = (f16)v.z; h[3] = (f16)v.w;
        *reinterpret_cast<f16x4*>(&sW[c][kq * 4]) = h;
    }
    __syncthreads();
    // ---- MFMA: 4 k-steps x 8 n-tiles ----
    #pragma unroll
    for (int ks = 0; ks < 4; ++ks) {
        f16x8 a = *reinterpret_cast<const f16x8*>(&sX[wave * 16 + lm][ks * 32 + lg * 8]);
        #pragma unroll
        for (int n0 = 0; n0 < 8; ++n0) {
            f16x8 b = *reinterpret_cast<const f16x8*>(&sW[n0 * 16 + lm][ks * 32 + lg * 8]);
            acc[n0] = __builtin_amdgcn_mfma_f32_16x16x32_f16(a, b, acc[n0], 0, 0, 0);
        }
    }
}

template<int ACT, bool X1H, bool X2H, bool O16>
__global__ __launch_bounds__(256, 3)
void gemm_dual_mfma(const void* __restrict__ X1, const float* __restrict__ W1, int ws1,
                    const void* __restrict__ X2, const float* __restrict__ W2, int ws2,
                    const float* __restrict__ bias, void* __restrict__ out, int M)
{
    __shared__ f16 sX[64][136];    // row stride 272 B (16B-aligned, banks spread)
    __shared__ f16 sW[128][136];
    const int tid  = threadIdx.x;
    const int row0 = blockIdx.x * 64;
    const int wave = tid >> 6;
    const int lane = tid & 63;
    const int lm   = lane & 15;
    const int lg   = lane >> 4;

    f32x4 acc[8];
    #pragma unroll
    for (int i = 0; i < 8; ++i) acc[i] = (f32x4){0.f, 0.f, 0.f, 0.f};

    stage_and_mfma<X1H>(X1, W1, ws1, sX, sW, tid, row0, M, wave, lm, lg, acc);
    stage_and_mfma<X2H>(X2, W2, ws2, sX, sW, tid, row0, M, wave, lm, lg, acc);

    // ---- epilogue: bias + act + store ----
    #pragma unroll
    for (int n0 = 0; n0 < 8; ++n0) {
        int col = n0 * 16 + lm;
        float bv = bias[col];
        #pragma unroll
        for (int r = 0; r < 4; ++r) {
            int row = row0 + wave * 16 + lg * 4 + r;
            if (row < M) {
                float o = acc[n0][r] + bv;
                if (ACT == 1) o = fmaxf(o, 0.f);
                else if (ACT == 2) o = o >= 0.f ? o : 0.2f * o;
                if (O16) ((f16*)out)[(size_t)row * D + col] = (f16)o;
                else     ((float*)out)[(size_t)row * D + col] = o;
            }
        }
    }
}

// ============================================================================
// CSR build: histogram -> exclusive scan -> fill (counting sort by dst)
// Edge payload packed as int2 {src, bitcast(weight)} -> one 8 B scattered store.
// ============================================================================
__global__ void hist_dst(const int* __restrict__ dst, int* __restrict__ cnt, int E)
{
    int e = blockIdx.x * blockDim.x + threadIdx.x;
    if (e < E) atomicAdd(&cnt[dst[e]], 1);
}

__global__ void scan_sums(const int* __restrict__ cnt, int* __restrict__ bsums, int n)
{
    __shared__ int sdata[256];
    int base = blockIdx.x * 1024;
    int t = threadIdx.x;
    int s = 0;
    #pragma unroll
    for (int j = 0; j < 4; ++j) {
        int i = base + t * 4 + j;
        if (i < n) s += cnt[i];
    }
    sdata[t] = s;
    __syncthreads();
    for (int off = 128; off > 0; off >>= 1) {
        if (t < off) sdata[t] += sdata[t + off];
        __syncthreads();
    }
    if (t == 0) bsums[blockIdx.x] = sdata[0];
}

__global__ void scan_bsums(int* __restrict__ bsums, int nb)
{
    if (blockIdx.x == 0 && threadIdx.x == 0) {
        int run = 0;
        for (int i = 0; i < nb; ++i) { int v = bsums[i]; bsums[i] = run; run += v; }
    }
}

__global__ void scan_apply(const int* __restrict__ cnt, const int* __restrict__ bsums,
                           int* __restrict__ rowptr, int* __restrict__ cursor, int n, int E)
{
    __shared__ int sthread[256];
    int base = blockIdx.x * 1024;
    int t = threadIdx.x;
    int vals[4]; int s = 0;
    #pragma unroll
    for (int j = 0; j < 4; ++j) {
        int i = base + t * 4 + j;
        vals[j] = (i < n) ? cnt[i] : 0;
        s += vals[j];
    }
    sthread[t] = s;
    __syncthreads();
    int pre = 0;
    for (int i = 0; i < t; ++i) pre += sthread[i];
    pre += bsums[blockIdx.x];
    #pragma unroll
    for (int j = 0; j < 4; ++j) {
        int i = base + t * 4 + j;
        if (i < n) { rowptr[i] = pre; cursor[i] = pre; pre += vals[j]; }
    }
    if (blockIdx.x == 0 && t == 0) rowptr[n] = E;
}

__global__ void fill_csr(const int* __restrict__ src, const int* __restrict__ dst,
                         const float* __restrict__ ew,
                         int* __restrict__ cursor, int2* __restrict__ epk, int E)
{
    int e = blockIdx.x * blockDim.x + threadIdx.x;
    if (e >= E) return;
    int p = atomicAdd(&cursor[dst[e]], 1);
    float w = ew ? ew[e] : 1.0f;
    epk[p] = make_int2(src[e], __float_as_int(w));
}

// ============================================================================
// Gather-side mean over f16 rows: one 64-lane wave per dst node, 4 edges in
// flight (quarter-wave h=0..3 handles edge beg+4i+h; 16 lanes x f16x8 = row).
// ============================================================================
__global__ __launch_bounds__(256)
void gather_mean16(const f16* __restrict__ X, const int* __restrict__ rowptr,
                   const int2* __restrict__ epk, f16* __restrict__ agg, int n)
{
    int t = blockIdx.x * blockDim.x + threadIdx.x;
    int node = t >> 6;
    if (node >= n) return;
    int lane = t & 63;
    int h = lane >> 4;     // quarter 0..3
    int q = lane & 15;     // 16 lanes x 8 f16 = 128 elems
    int beg = rowptr[node], end = rowptr[node + 1];
    float acc[8] = {};
    for (int e = beg + h; e < end; e += 4) {
        int2 p = epk[e];
        float w = __int_as_float(p.y);
        f16x8 v = *reinterpret_cast<const f16x8*>(X + (size_t)p.x * D + q * 8);
        #pragma unroll
        for (int j = 0; j < 8; ++j) acc[j] = fmaf((float)v[j], w, acc[j]);
    }
    #pragma unroll
    for (int j = 0; j < 8; ++j) {
        acc[j] += __shfl_xor(acc[j], 16);
        acc[j] += __shfl_xor(acc[j], 32);
    }
    if (h == 0) {
        float inv = 1.0f / fmaxf((float)(end - beg), 1.0f);
        f16x8 o;
        #pragma unroll
        for (int j = 0; j < 8; ++j) o[j] = (f16)(acc[j] * inv);
        *reinterpret_cast<f16x8*>(agg + (size_t)node * D + q * 8) = o;
    }
}

// ============================================================================
// Weight folding:  S1f = W2 @ S1, N1f = W2 @ N1, b1f = W2 @ b1 + w2_b
//                  T1f = W3 @ T1, U1f = W3 @ U1, e1f = W3 @ e1 + w3_b
// ============================================================================
__global__ void fold_weights(const float* __restrict__ w2_W, const float* __restrict__ w2_b,
                             const float* __restrict__ S1, const float* __restrict__ N1,
                             const float* __restrict__ b1,
                             const float* __restrict__ w3_W, const float* __restrict__ w3_b,
                             const float* __restrict__ T1, const float* __restrict__ U1,
                             const float* __restrict__ e1,
                             float* __restrict__ S1f, float* __restrict__ N1f, float* __restrict__ b1f,
                             float* __restrict__ T1f, float* __restrict__ U1f, float* __restrict__ e1f)
{
    int b = blockIdx.x;
    int tid = threadIdx.x;
    if (b < 256) {
        int m = b >> 6;
        const float* WA = (m < 2) ? w2_W : w3_W;
        const float* SB = (m == 0) ? S1 : (m == 1) ? N1 : (m == 2) ? T1 : U1;
        float* O        = (m == 0) ? S1f : (m == 1) ? N1f : (m == 2) ? T1f : U1f;
        int elem = (b & 63) * 256 + tid;
        int i = elem >> 7;
        int k = elem & 127;
        float sum = 0.f;
        for (int j = 0; j < 128; ++j)
            sum = fmaf(WA[i * 128 + j], SB[j * 128 + k], sum);
        O[elem] = sum;
    } else if (b == 256) {
        if (tid < 128) {
            float sum = w2_b[tid];
            for (int j = 0; j < 128; ++j) sum = fmaf(w2_W[tid * 128 + j], b1[j], sum);
            b1f[tid] = sum;
        }
    } else {
        if (tid < 128) {
            float sum = w3_b[tid];
            for (int j = 0; j < 128; ++j) sum = fmaf(w3_W[tid * 128 + j], e1[j], sum);
            e1f[tid] = sum;
        }
    }
}

// ============================================================================
extern "C" void kernel_launch(void* const* d_in, const int* in_sizes, int n_in,
                              void* d_out, int out_size, void* d_ws, size_t ws_size,
                              hipStream_t stream)
{
    const float* ii      = (const float*)d_in[0];
    const float* e_emb   = (const float*)d_in[1];
    const float* kemb    = (const float*)d_in[2];
    const float* cf_ew   = (const float*)d_in[3];
    const int*   b_src   = (const int*)d_in[4];
    const int*   b_dst   = (const int*)d_in[5];
    const int*   c_src   = (const int*)d_in[6];
    const int*   c_dst   = (const int*)d_in[7];
    const float* ek_self = (const float*)d_in[8];
    const float* ek_neigh= (const float*)d_in[9];
    const float* ek_bias = (const float*)d_in[10];
    const float* ee_self = (const float*)d_in[11];
    const float* ee_neigh= (const float*)d_in[12];
    const float* ee_bias = (const float*)d_in[13];
    const float* w1_W    = (const float*)d_in[14];
    const float* w1_b    = (const float*)d_in[15];
    const float* w2_W    = (const float*)d_in[16];
    const float* w2_b    = (const float*)d_in[17];
    const float* w3_W    = (const float*)d_in[18];
    const float* w3_b    = (const float*)d_in[19];
    const float* w4_W    = (const float*)d_in[20];
    const float* w4_b    = (const float*)d_in[21];
    const float* comb_W  = (const float*)d_in[22];
    const float* comb_b  = (const float*)d_in[23];

    const int n_k = in_sizes[0] / D;    // 10000
    const int n_e = in_sizes[1] / D;    // 100000
    const int E   = in_sizes[4];        // 1600000

    // ---- workspace layout (~93 MB) ----
    char* wsb = (char*)d_ws;
    auto align256 = [](size_t x) { return (x + 255) & ~(size_t)255; };
    const size_t row16 = align256((size_t)n_e * D * sizeof(f16));     // 25.6 MB
    f16*  A16    = (f16*)wsb;   wsb += row16;   // dst1 / src_com / dst1c / h_iS
    f16*  AGG16  = (f16*)wsb;   wsb += row16;   // neighbor means
    f16*  H16    = (f16*)wsb;   wsb += row16;   // h_iI
    f16*  II2    = (f16*)wsb;   wsb += align256((size_t)n_k * D * sizeof(f16));
    int*  rowptr = (int*)wsb;   wsb += align256((size_t)(n_e + 1) * sizeof(int));
    int*  cursor = (int*)wsb;   wsb += align256((size_t)n_e * sizeof(int));
    int2* epk    = (int2*)wsb;  wsb += align256((size_t)E * sizeof(int2));   // 12.8 MB
    int*  bsums  = (int*)wsb;   wsb += 4096;
    float* S1f   = (float*)wsb; wsb += D * D * sizeof(float);
    float* N1f   = (float*)wsb; wsb += D * D * sizeof(float);
    float* T1f   = (float*)wsb; wsb += D * D * sizeof(float);
    float* U1f   = (float*)wsb; wsb += D * D * sizeof(float);
    float* b1f   = (float*)wsb; wsb += 256;
    float* e1f   = (float*)wsb; wsb += 256;
    float* OUT   = (float*)d_out;

    const int gemmGridE = (n_e + 63) / 64;
    const int gemmGridK = (n_k + 63) / 64;
    const int edgeGrid  = (E + 255) / 256;
    const int scanNB    = (n_e + 1023) / 1024;        // 98
    const int gathGrid  = (n_e * 64 + 255) / 256;     // 25000

    // 0) fold layer-1 weights through w2 / w3
    fold_weights<<<258, 256, 0, stream>>>(w2_W, w2_b,
        ek_self + D*D, ek_neigh + D*D, ek_bias + D,
        w3_W, w3_b,
        ee_self + D*D, ee_neigh + D*D, ee_bias + D,
        S1f, N1f, b1f, T1f, U1f, e1f);

    // 1) ii2 = [ii ; kemb] @ w4^T + b4  -> f16
    gemm_dual_mfma<0, false, false, true><<<gemmGridK, 256, 0, stream>>>(
        ii, w4_W, 2*D, kemb, w4_W + D, 2*D, w4_b, II2, n_k);

    // 2) belong graph: CSR build + gather mean of II2
    hipMemsetAsync(cursor, 0, (size_t)n_e * sizeof(int), stream);
    hist_dst<<<edgeGrid, 256, 0, stream>>>(b_dst, cursor, E);
    scan_sums<<<scanNB, 256, 0, stream>>>(cursor, bsums, n_e);
    scan_bsums<<<1, 64, 0, stream>>>(bsums, scanNB);
    scan_apply<<<scanNB, 256, 0, stream>>>(cursor, bsums, rowptr, cursor, n_e, E);
    fill_csr<<<edgeGrid, 256, 0, stream>>>(b_src, b_dst, nullptr, cursor, epk, E);
    gather_mean16<<<gathGrid, 256, 0, stream>>>(II2, rowptr, epk, AGG16, n_e);

    // 3) dst1 = relu(e_emb@S0^T + neigh@N0^T + b0) -> A16
    gemm_dual_mfma<1, false, true, true><<<gemmGridE, 256, 0, stream>>>(
        e_emb, ek_self, D, AGG16, ek_neigh, D, ek_bias, A16, n_e);

    // 4) h_iI = dst1@S1f^T + neigh@N1f^T + b1f  (w2 folded) -> H16
    gemm_dual_mfma<0, true, true, true><<<gemmGridE, 256, 0, stream>>>(
        A16, S1f, D, AGG16, N1f, D, b1f, H16, n_e);

    // 5) src_com = [h_iI ; e_emb] @ w1^T + b1 -> A16 (dst1 dead)
    gemm_dual_mfma<0, true, false, true><<<gemmGridE, 256, 0, stream>>>(
        H16, w1_W, 2*D, e_emb, w1_W + D, 2*D, w1_b, A16, n_e);

    // 6) collab graph: CSR build + edge-weighted gather mean of src_com
    hipMemsetAsync(cursor, 0, (size_t)n_e * sizeof(int), stream);
    hist_dst<<<edgeGrid, 256, 0, stream>>>(c_dst, cursor, E);
    scan_sums<<<scanNB, 256, 0, stream>>>(cursor, bsums, n_e);
    scan_bsums<<<1, 64, 0, stream>>>(bsums, scanNB);
    scan_apply<<<scanNB, 256, 0, stream>>>(cursor, bsums, rowptr, cursor, n_e, E);
    fill_csr<<<edgeGrid, 256, 0, stream>>>(c_src, c_dst, cf_ew, cursor, epk, E);
    gather_mean16<<<gathGrid, 256, 0, stream>>>(A16, rowptr, epk, AGG16, n_e);

    // 7) dst1c = relu(e_emb@T0^T + neigh_c@U0^T + eb0) -> A16 (src_com dead)
    gemm_dual_mfma<1, false, true, true><<<gemmGridE, 256, 0, stream>>>(
        e_emb, ee_self, D, AGG16, ee_neigh, D, ee_bias, A16, n_e);

    // 8) h_iS = dst1c@T1f^T + neigh_c@U1f^T + e1f  (w3 folded) -> A16 in place
    gemm_dual_mfma<0, true, true, true><<<gemmGridE, 256, 0, stream>>>(
        A16, T1f, D, AGG16, U1f, D, e1f, A16, n_e);

    // 9) out = leaky( [h_iI ; h_iS] @ comb^T + cb ) -> d_out f32
    gemm_dual_mfma<2, true, true, false><<<gemmGridE, 256, 0, stream>>>(
        H16, comb_W, 2*D, A16, comb_W + D, 2*D, comb_b, OUT, n_e);
}

// Round 10
// 805.560 us; speedup vs baseline: 8.0702x; 1.0858x over previous
//
#include <hip/hip_runtime.h>

#define D 128

using f16   = _Float16;
using f16x4 = __attribute__((ext_vector_type(4))) _Float16;
using f16x8 = __attribute__((ext_vector_type(8))) _Float16;
using f32x4 = __attribute__((ext_vector_type(4))) float;

__device__ __forceinline__ f16x8 zero8() {
    f16x8 v;
    #pragma unroll
    for (int j = 0; j < 8; ++j) v[j] = (f16)0;
    return v;
}

// ---- staging helpers (validated rounds 7-8) ------------------------------
__device__ __forceinline__ void stageX32(const float* __restrict__ X, f16 (*sX)[136],
                                         int tid, int row0, int M)
{
    #pragma unroll
    for (int i = 0; i < 8; ++i) {
        int idx = i * 256 + tid;
        int r = idx >> 5, kq = idx & 31;
        float4 v = make_float4(0.f, 0.f, 0.f, 0.f);
        int gr = row0 + r;
        if (gr < M) v = *reinterpret_cast<const float4*>(X + (size_t)gr * D + kq * 4);
        f16x4 h; h[0] = (f16)v.x; h[1] = (f16)v.y; h[2] = (f16)v.z; h[3] = (f16)v.w;
        *reinterpret_cast<f16x4*>(&sX[r][kq * 4]) = h;
    }
}

__device__ __forceinline__ void stageX16(const f16* __restrict__ X, f16 (*sX)[136],
                                         int tid, int row0, int M)
{
    #pragma unroll
    for (int i = 0; i < 4; ++i) {
        int idx = i * 256 + tid;
        int r = idx >> 4, kc = idx & 15;
        f16x8 v = zero8();
        int gr = row0 + r;
        if (gr < M) v = *reinterpret_cast<const f16x8*>(X + (size_t)gr * D + kc * 8);
        *reinterpret_cast<f16x8*>(&sX[r][kc * 8]) = v;
    }
}

__device__ __forceinline__ void stageW(const float* __restrict__ W, int ws,
                                       f16 (*sW)[136], int tid)
{
    #pragma unroll
    for (int i = 0; i < 16; ++i) {
        int idx = i * 256 + tid;
        int c = idx >> 5, kq = idx & 31;
        float4 v = *reinterpret_cast<const float4*>(W + (size_t)c * ws + kq * 4);
        f16x4 h; h[0] = (f16)v.x; h[1] = (f16)v.y; h[2] = (f16)v.z; h[3] = (f16)v.w;
        *reinterpret_cast<f16x4*>(&sW[c][kq * 4]) = h;
    }
}

// K=128 MFMA sweep: wave's 16 rows of sA x 128 cols of sW -> acc[8] (f32x4)
__device__ __forceinline__ void mfma8(const f16 (*sA)[136], const f16 (*sW)[136],
                                      int wave, int lm, int lg, f32x4 acc[8])
{
    #pragma unroll
    for (int ks = 0; ks < 4; ++ks) {
        f16x8 a = *reinterpret_cast<const f16x8*>(&sA[wave * 16 + lm][ks * 32 + lg * 8]);
        #pragma unroll
        for (int n0 = 0; n0 < 8; ++n0) {
            f16x8 b = *reinterpret_cast<const f16x8*>(&sW[n0 * 16 + lm][ks * 32 + lg * 8]);
            acc[n0] = __builtin_amdgcn_mfma_f32_16x16x32_f16(a, b, acc[n0], 0, 0, 0);
        }
    }
}

// ============================================================================
// Fused knowledge-graph chain (old steps 3,4,5):
//   dst1    = relu(e_emb@S0^T + agg@N0^T + b0)          [stays in LDS]
//   h_iI    = dst1@S1f^T + agg@N1f^T + b1f              -> H16
//   src_com = h_iI@w1A^T + e_emb@w1B^T + w1_b           -> A16
// A-fragments read only the wave's own 16 rows -> no cross-wave LDS hazards.
// ============================================================================
__global__ __launch_bounds__(256, 2)
void fused_ek(const float* __restrict__ e_emb, const f16* __restrict__ agg,
              const float* __restrict__ S0, const float* __restrict__ N0,
              const float* __restrict__ b0,
              const float* __restrict__ S1f, const float* __restrict__ N1f,
              const float* __restrict__ b1f,
              const float* __restrict__ w1W, const float* __restrict__ w1b,
              f16* __restrict__ H16, f16* __restrict__ A16, int M)
{
    __shared__ f16 sE[64][136];   // e_emb -> dst1 -> h_iI
    __shared__ f16 sG[64][136];   // agg
    __shared__ f16 sW[128][136];  // current weight
    const int tid = threadIdx.x, row0 = blockIdx.x * 64;
    const int wave = tid >> 6, lane = tid & 63, lm = lane & 15, lg = lane >> 4;

    f32x4 acc1[8], acc2[8];
    #pragma unroll
    for (int i = 0; i < 8; ++i) { acc1[i] = (f32x4){0,0,0,0}; acc2[i] = (f32x4){0,0,0,0}; }

    // P1: acc1 = E@S0
    stageX32(e_emb, sE, tid, row0, M);
    stageW(S0, D, sW, tid);
    __syncthreads();
    mfma8(sE, sW, wave, lm, lg, acc1);
    // P2: acc2 = E@w1B   (second half of w1; e_emb dead after)
    __syncthreads();
    stageW(w1W + D, 2 * D, sW, tid);
    __syncthreads();
    mfma8(sE, sW, wave, lm, lg, acc2);
    // P3: acc1 += G@N0
    __syncthreads();
    stageX16(agg, sG, tid, row0, M);
    stageW(N0, D, sW, tid);
    __syncthreads();
    mfma8(sG, sW, wave, lm, lg, acc1);
    // dst1 = relu(acc1 + b0) -> sE (own rows only)
    #pragma unroll
    for (int n0 = 0; n0 < 8; ++n0) {
        int col = n0 * 16 + lm;
        float bv = b0[col];
        #pragma unroll
        for (int r = 0; r < 4; ++r) {
            float v = fmaxf(acc1[n0][r] + bv, 0.f);
            sE[wave * 16 + lg * 4 + r][col] = (f16)v;
        }
    }
    // P4: acc1 = D@S1f
    __syncthreads();
    stageW(S1f, D, sW, tid);
    __syncthreads();
    #pragma unroll
    for (int i = 0; i < 8; ++i) acc1[i] = (f32x4){0,0,0,0};
    mfma8(sE, sW, wave, lm, lg, acc1);
    // P5: acc1 += G@N1f ; h_iI -> H16 + sE
    __syncthreads();
    stageW(N1f, D, sW, tid);
    __syncthreads();
    mfma8(sG, sW, wave, lm, lg, acc1);
    #pragma unroll
    for (int n0 = 0; n0 < 8; ++n0) {
        int col = n0 * 16 + lm;
        float bv = b1f[col];
        #pragma unroll
        for (int r = 0; r < 4; ++r) {
            int row = row0 + wave * 16 + lg * 4 + r;
            float v = acc1[n0][r] + bv;
            sE[wave * 16 + lg * 4 + r][col] = (f16)v;
            if (row < M) H16[(size_t)row * D + col] = (f16)v;
        }
    }
    // P6: acc2 += H@w1A ; src_com -> A16
    __syncthreads();
    stageW(w1W, 2 * D, sW, tid);
    __syncthreads();
    mfma8(sE, sW, wave, lm, lg, acc2);
    #pragma unroll
    for (int n0 = 0; n0 < 8; ++n0) {
        int col = n0 * 16 + lm;
        float bv = w1b[col];
        #pragma unroll
        for (int r = 0; r < 4; ++r) {
            int row = row0 + wave * 16 + lg * 4 + r;
            if (row < M) A16[(size_t)row * D + col] = (f16)(acc2[n0][r] + bv);
        }
    }
}

// ============================================================================
// Fused employee-graph chain (old steps 7,8):
//   dst1c = relu(e_emb@T0^T + agg@U0^T + eb0)   [LDS]
//   h_iS  = dst1c@T1f^T + agg@U1f^T + e1f       -> A16
// ============================================================================
__global__ __launch_bounds__(256, 2)
void fused_ee(const float* __restrict__ e_emb, const f16* __restrict__ agg,
              const float* __restrict__ T0, const float* __restrict__ U0,
              const float* __restrict__ eb0,
              const float* __restrict__ T1f, const float* __restrict__ U1f,
              const float* __restrict__ e1f,
              f16* __restrict__ A16, int M)
{
    __shared__ f16 sE[64][136];
    __shared__ f16 sG[64][136];
    __shared__ f16 sW[128][136];
    const int tid = threadIdx.x, row0 = blockIdx.x * 64;
    const int wave = tid >> 6, lane = tid & 63, lm = lane & 15, lg = lane >> 4;

    f32x4 acc1[8];
    #pragma unroll
    for (int i = 0; i < 8; ++i) acc1[i] = (f32x4){0,0,0,0};

    // P1: acc1 = E@T0
    stageX32(e_emb, sE, tid, row0, M);
    stageW(T0, D, sW, tid);
    __syncthreads();
    mfma8(sE, sW, wave, lm, lg, acc1);
    // P2: acc1 += G@U0 ; dst1c -> sE
    __syncthreads();
    stageX16(agg, sG, tid, row0, M);
    stageW(U0, D, sW, tid);
    __syncthreads();
    mfma8(sG, sW, wave, lm, lg, acc1);
    #pragma unroll
    for (int n0 = 0; n0 < 8; ++n0) {
        int col = n0 * 16 + lm;
        float bv = eb0[col];
        #pragma unroll
        for (int r = 0; r < 4; ++r) {
            float v = fmaxf(acc1[n0][r] + bv, 0.f);
            sE[wave * 16 + lg * 4 + r][col] = (f16)v;
        }
    }
    // P3: acc1 = D@T1f
    __syncthreads();
    stageW(T1f, D, sW, tid);
    __syncthreads();
    #pragma unroll
    for (int i = 0; i < 8; ++i) acc1[i] = (f32x4){0,0,0,0};
    mfma8(sE, sW, wave, lm, lg, acc1);
    // P4: acc1 += G@U1f ; h_iS -> A16
    __syncthreads();
    stageW(U1f, D, sW, tid);
    __syncthreads();
    mfma8(sG, sW, wave, lm, lg, acc1);
    #pragma unroll
    for (int n0 = 0; n0 < 8; ++n0) {
        int col = n0 * 16 + lm;
        float bv = e1f[col];
        #pragma unroll
        for (int r = 0; r < 4; ++r) {
            int row = row0 + wave * 16 + lg * 4 + r;
            if (row < M) A16[(size_t)row * D + col] = (f16)(acc1[n0][r] + bv);
        }
    }
}

// ============================================================================
// Dual-source MFMA GEMM (steps 1 and 9 only), validated rounds 7-8.
// ============================================================================
template<bool H>
__device__ __forceinline__ void stage_and_mfma(
    const void* Xv, const float* W, int ws,
    f16 (*sX)[136], f16 (*sW)[136],
    int tid, int row0, int M, int wave, int lm, int lg, f32x4 acc[8])
{
    __syncthreads();
    if (H) stageX16((const f16*)Xv, sX, tid, row0, M);
    else   stageX32((const float*)Xv, sX, tid, row0, M);
    stageW(W, ws, sW, tid);
    __syncthreads();
    mfma8(sX, sW, wave, lm, lg, acc);
}

template<int ACT, bool X1H, bool X2H, bool O16>
__global__ __launch_bounds__(256, 3)
void gemm_dual_mfma(const void* __restrict__ X1, const float* __restrict__ W1, int ws1,
                    const void* __restrict__ X2, const float* __restrict__ W2, int ws2,
                    const float* __restrict__ bias, void* __restrict__ out, int M)
{
    __shared__ f16 sX[64][136];
    __shared__ f16 sW[128][136];
    const int tid = threadIdx.x, row0 = blockIdx.x * 64;
    const int wave = tid >> 6, lane = tid & 63, lm = lane & 15, lg = lane >> 4;

    f32x4 acc[8];
    #pragma unroll
    for (int i = 0; i < 8; ++i) acc[i] = (f32x4){0,0,0,0};

    stage_and_mfma<X1H>(X1, W1, ws1, sX, sW, tid, row0, M, wave, lm, lg, acc);
    stage_and_mfma<X2H>(X2, W2, ws2, sX, sW, tid, row0, M, wave, lm, lg, acc);

    #pragma unroll
    for (int n0 = 0; n0 < 8; ++n0) {
        int col = n0 * 16 + lm;
        float bv = bias[col];
        #pragma unroll
        for (int r = 0; r < 4; ++r) {
            int row = row0 + wave * 16 + lg * 4 + r;
            if (row < M) {
                float o = acc[n0][r] + bv;
                if (ACT == 1) o = fmaxf(o, 0.f);
                else if (ACT == 2) o = o >= 0.f ? o : 0.2f * o;
                if (O16) ((f16*)out)[(size_t)row * D + col] = (f16)o;
                else     ((float*)out)[(size_t)row * D + col] = o;
            }
        }
    }
}

// ============================================================================
// CSR build: histogram -> exclusive scan -> fill (counting sort by dst)
// ============================================================================
__global__ void hist_dst(const int* __restrict__ dst, int* __restrict__ cnt, int E)
{
    int e = blockIdx.x * blockDim.x + threadIdx.x;
    if (e < E) atomicAdd(&cnt[dst[e]], 1);
}

__global__ void scan_sums(const int* __restrict__ cnt, int* __restrict__ bsums, int n)
{
    __shared__ int sdata[256];
    int base = blockIdx.x * 1024;
    int t = threadIdx.x;
    int s = 0;
    #pragma unroll
    for (int j = 0; j < 4; ++j) {
        int i = base + t * 4 + j;
        if (i < n) s += cnt[i];
    }
    sdata[t] = s;
    __syncthreads();
    for (int off = 128; off > 0; off >>= 1) {
        if (t < off) sdata[t] += sdata[t + off];
        __syncthreads();
    }
    if (t == 0) bsums[blockIdx.x] = sdata[0];
}

__global__ void scan_bsums(int* __restrict__ bsums, int nb)
{
    if (blockIdx.x == 0 && threadIdx.x == 0) {
        int run = 0;
        for (int i = 0; i < nb; ++i) { int v = bsums[i]; bsums[i] = run; run += v; }
    }
}

__global__ void scan_apply(const int* __restrict__ cnt, const int* __restrict__ bsums,
                           int* __restrict__ rowptr, int* __restrict__ cursor, int n, int E)
{
    __shared__ int sthread[256];
    int base = blockIdx.x * 1024;
    int t = threadIdx.x;
    int vals[4]; int s = 0;
    #pragma unroll
    for (int j = 0; j < 4; ++j) {
        int i = base + t * 4 + j;
        vals[j] = (i < n) ? cnt[i] : 0;
        s += vals[j];
    }
    sthread[t] = s;
    __syncthreads();
    int pre = 0;
    for (int i = 0; i < t; ++i) pre += sthread[i];
    pre += bsums[blockIdx.x];
    #pragma unroll
    for (int j = 0; j < 4; ++j) {
        int i = base + t * 4 + j;
        if (i < n) { rowptr[i] = pre; cursor[i] = pre; pre += vals[j]; }
    }
    if (blockIdx.x == 0 && t == 0) rowptr[n] = E;
}

__global__ void fill_csr(const int* __restrict__ src, const int* __restrict__ dst,
                         const float* __restrict__ ew,
                         int* __restrict__ cursor, int2* __restrict__ epk, int E)
{
    int e = blockIdx.x * blockDim.x + threadIdx.x;
    if (e >= E) return;
    int p = atomicAdd(&cursor[dst[e]], 1);
    float w = ew ? ew[e] : 1.0f;
    epk[p] = make_int2(src[e], __float_as_int(w));
}

// ============================================================================
// Gather-side mean over f16 rows: one 64-lane wave per dst node, 4 edges in
// flight (quarter-wave h=0..3; 16 lanes x f16x8 = one 256 B row).
// ============================================================================
__global__ __launch_bounds__(256)
void gather_mean16(const f16* __restrict__ X, const int* __restrict__ rowptr,
                   const int2* __restrict__ epk, f16* __restrict__ agg, int n)
{
    int t = blockIdx.x * blockDim.x + threadIdx.x;
    int node = t >> 6;
    if (node >= n) return;
    int lane = t & 63;
    int h = lane >> 4;
    int q = lane & 15;
    int beg = rowptr[node], end = rowptr[node + 1];
    float acc[8] = {};
    for (int e = beg + h; e < end; e += 4) {
        int2 p = epk[e];
        float w = __int_as_float(p.y);
        f16x8 v = *reinterpret_cast<const f16x8*>(X + (size_t)p.x * D + q * 8);
        #pragma unroll
        for (int j = 0; j < 8; ++j) acc[j] = fmaf((float)v[j], w, acc[j]);
    }
    #pragma unroll
    for (int j = 0; j < 8; ++j) {
        acc[j] += __shfl_xor(acc[j], 16);
        acc[j] += __shfl_xor(acc[j], 32);
    }
    if (h == 0) {
        float inv = 1.0f / fmaxf((float)(end - beg), 1.0f);
        f16x8 o;
        #pragma unroll
        for (int j = 0; j < 8; ++j) o[j] = (f16)(acc[j] * inv);
        *reinterpret_cast<f16x8*>(agg + (size_t)node * D + q * 8) = o;
    }
}

// ============================================================================
// Weight folding (unchanged)
// ============================================================================
__global__ void fold_weights(const float* __restrict__ w2_W, const float* __restrict__ w2_b,
                             const float* __restrict__ S1, const float* __restrict__ N1,
                             const float* __restrict__ b1,
                             const float* __restrict__ w3_W, const float* __restrict__ w3_b,
                             const float* __restrict__ T1, const float* __restrict__ U1,
                             const float* __restrict__ e1,
                             float* __restrict__ S1f, float* __restrict__ N1f, float* __restrict__ b1f,
                             float* __restrict__ T1f, float* __restrict__ U1f, float* __restrict__ e1f)
{
    int b = blockIdx.x;
    int tid = threadIdx.x;
    if (b < 256) {
        int m = b >> 6;
        const float* WA = (m < 2) ? w2_W : w3_W;
        const float* SB = (m == 0) ? S1 : (m == 1) ? N1 : (m == 2) ? T1 : U1;
        float* O        = (m == 0) ? S1f : (m == 1) ? N1f : (m == 2) ? T1f : U1f;
        int elem = (b & 63) * 256 + tid;
        int i = elem >> 7;
        int k = elem & 127;
        float sum = 0.f;
        for (int j = 0; j < 128; ++j)
            sum = fmaf(WA[i * 128 + j], SB[j * 128 + k], sum);
        O[elem] = sum;
    } else if (b == 256) {
        if (tid < 128) {
            float sum = w2_b[tid];
            for (int j = 0; j < 128; ++j) sum = fmaf(w2_W[tid * 128 + j], b1[j], sum);
            b1f[tid] = sum;
        }
    } else {
        if (tid < 128) {
            float sum = w3_b[tid];
            for (int j = 0; j < 128; ++j) sum = fmaf(w3_W[tid * 128 + j], e1[j], sum);
            e1f[tid] = sum;
        }
    }
}

// ============================================================================
extern "C" void kernel_launch(void* const* d_in, const int* in_sizes, int n_in,
                              void* d_out, int out_size, void* d_ws, size_t ws_size,
                              hipStream_t stream)
{
    const float* ii      = (const float*)d_in[0];
    const float* e_emb   = (const float*)d_in[1];
    const float* kemb    = (const float*)d_in[2];
    const float* cf_ew   = (const float*)d_in[3];
    const int*   b_src   = (const int*)d_in[4];
    const int*   b_dst   = (const int*)d_in[5];
    const int*   c_src   = (const int*)d_in[6];
    const int*   c_dst   = (const int*)d_in[7];
    const float* ek_self = (const float*)d_in[8];
    const float* ek_neigh= (const float*)d_in[9];
    const float* ek_bias = (const float*)d_in[10];
    const float* ee_self = (const float*)d_in[11];
    const float* ee_neigh= (const float*)d_in[12];
    const float* ee_bias = (const float*)d_in[13];
    const float* w1_W    = (const float*)d_in[14];
    const float* w1_b    = (const float*)d_in[15];
    const float* w2_W    = (const float*)d_in[16];
    const float* w2_b    = (const float*)d_in[17];
    const float* w3_W    = (const float*)d_in[18];
    const float* w3_b    = (const float*)d_in[19];
    const float* w4_W    = (const float*)d_in[20];
    const float* w4_b    = (const float*)d_in[21];
    const float* comb_W  = (const float*)d_in[22];
    const float* comb_b  = (const float*)d_in[23];

    const int n_k = in_sizes[0] / D;    // 10000
    const int n_e = in_sizes[1] / D;    // 100000
    const int E   = in_sizes[4];        // 1600000

    // ---- workspace layout (~93 MB) ----
    char* wsb = (char*)d_ws;
    auto align256 = [](size_t x) { return (x + 255) & ~(size_t)255; };
    const size_t row16 = align256((size_t)n_e * D * sizeof(f16));     // 25.6 MB
    f16*  A16    = (f16*)wsb;   wsb += row16;   // src_com / h_iS
    f16*  AGG16  = (f16*)wsb;   wsb += row16;   // neighbor means
    f16*  H16    = (f16*)wsb;   wsb += row16;   // h_iI
    f16*  II2    = (f16*)wsb;   wsb += align256((size_t)n_k * D * sizeof(f16));
    int*  rowptr = (int*)wsb;   wsb += align256((size_t)(n_e + 1) * sizeof(int));
    int*  cursor = (int*)wsb;   wsb += align256((size_t)n_e * sizeof(int));
    int2* epk    = (int2*)wsb;  wsb += align256((size_t)E * sizeof(int2));   // 12.8 MB
    int*  bsums  = (int*)wsb;   wsb += 4096;
    float* S1f   = (float*)wsb; wsb += D * D * sizeof(float);
    float* N1f   = (float*)wsb; wsb += D * D * sizeof(float);
    float* T1f   = (float*)wsb; wsb += D * D * sizeof(float);
    float* U1f   = (float*)wsb; wsb += D * D * sizeof(float);
    float* b1f   = (float*)wsb; wsb += 256;
    float* e1f   = (float*)wsb; wsb += 256;
    float* OUT   = (float*)d_out;

    const int gemmGridE = (n_e + 63) / 64;
    const int gemmGridK = (n_k + 63) / 64;
    const int edgeGrid  = (E + 255) / 256;
    const int scanNB    = (n_e + 1023) / 1024;        // 98
    const int gathGrid  = (n_e * 64 + 255) / 256;     // 25000

    // 0) fold layer-1 weights through w2 / w3
    fold_weights<<<258, 256, 0, stream>>>(w2_W, w2_b,
        ek_self + D*D, ek_neigh + D*D, ek_bias + D,
        w3_W, w3_b,
        ee_self + D*D, ee_neigh + D*D, ee_bias + D,
        S1f, N1f, b1f, T1f, U1f, e1f);

    // 1) ii2 = [ii ; kemb] @ w4^T + b4  -> f16
    gemm_dual_mfma<0, false, false, true><<<gemmGridK, 256, 0, stream>>>(
        ii, w4_W, 2*D, kemb, w4_W + D, 2*D, w4_b, II2, n_k);

    // 2) belong graph: CSR build + gather mean of II2
    hipMemsetAsync(cursor, 0, (size_t)n_e * sizeof(int), stream);
    hist_dst<<<edgeGrid, 256, 0, stream>>>(b_dst, cursor, E);
    scan_sums<<<scanNB, 256, 0, stream>>>(cursor, bsums, n_e);
    scan_bsums<<<1, 64, 0, stream>>>(bsums, scanNB);
    scan_apply<<<scanNB, 256, 0, stream>>>(cursor, bsums, rowptr, cursor, n_e, E);
    fill_csr<<<edgeGrid, 256, 0, stream>>>(b_src, b_dst, nullptr, cursor, epk, E);
    gather_mean16<<<gathGrid, 256, 0, stream>>>(II2, rowptr, epk, AGG16, n_e);

    // 3-5) fused knowledge chain: dst1 (LDS), h_iI -> H16, src_com -> A16
    fused_ek<<<gemmGridE, 256, 0, stream>>>(
        e_emb, AGG16, ek_self, ek_neigh, ek_bias,
        S1f, N1f, b1f, w1_W, w1_b, H16, A16, n_e);

    // 6) collab graph: CSR build + edge-weighted gather mean of src_com
    hipMemsetAsync(cursor, 0, (size_t)n_e * sizeof(int), stream);
    hist_dst<<<edgeGrid, 256, 0, stream>>>(c_dst, cursor, E);
    scan_sums<<<scanNB, 256, 0, stream>>>(cursor, bsums, n_e);
    scan_bsums<<<1, 64, 0, stream>>>(bsums, scanNB);
    scan_apply<<<scanNB, 256, 0, stream>>>(cursor, bsums, rowptr, cursor, n_e, E);
    fill_csr<<<edgeGrid, 256, 0, stream>>>(c_src, c_dst, cf_ew, cursor, epk, E);
    gather_mean16<<<gathGrid, 256, 0, stream>>>(A16, rowptr, epk, AGG16, n_e);

    // 7-8) fused employee chain: dst1c (LDS), h_iS -> A16
    fused_ee<<<gemmGridE, 256, 0, stream>>>(
        e_emb, AGG16, ee_self, ee_neigh, ee_bias,
        T1f, U1f, e1f, A16, n_e);

    // 9) out = leaky( [h_iI ; h_iS] @ comb^T + cb ) -> d_out f32
    gemm_dual_mfma<2, true, true, false><<<gemmGridE, 256, 0, stream>>>(
        H16, comb_W, 2*D, A16, comb_W + D, 2*D, comb_b, OUT, n_e);
}